// Round 1
// baseline (146.985 us; speedup 1.0000x reference)
//
#include <hip/hip_runtime.h>
#include <cstdint>

typedef __attribute__((ext_vector_type(8))) short bf16x8;    // 8 bf16 = 4 VGPRs
typedef __attribute__((ext_vector_type(16))) float f32x16;   // 32x32 MFMA C/D
typedef __attribute__((ext_vector_type(4))) float f4;
typedef __attribute__((ext_vector_type(8))) unsigned short u16x8;
typedef unsigned short u16;

// JOURNAL:
// R6: __launch_bounds__(256,6) forced VGPR 72->40, scratch spills (+36MB traffic).
// R7: device-scope __threadfence() reduction inside gemm3 = L2 writeback storms.
// R8: (256,8) neutral; residency saturated ~4 blocks/CU.
// R9: 32x32x16 MFMA beats 16x16x32 (-5us). BEST = 148.4us.
// R10: 256x64/KSPLIT=8 neutral (mainloop at plateau?) -- confounded: intensity
//      only 44->52 F/B AND doubled partial traffic. Not a clean test.
// R11: bf16 partials + 1024-block reduce CRASHED (GPU abort). part aliased the
//      cast region with an exact-boundary fit. R12: identical logic, part moved
//      to a dedicated non-aliased region (only variable changed).
// R13 (this round): TN 64->128 both GEMMs. 44->66 FLOP/staged-byte (m97 parity),
//      16 MFMA/K-step/wave between barriers. Wave grid 2x2 over 128x128, acc[2][2].
//      gemm12 grid (36,16); gemm3 grid (32,4,4), partial bytes unchanged;
//      reduce4 remapped (8 chunks x 128 tiles). Predict GEMMs ~41->~24us each.

__device__ __forceinline__ u16 f2bf(float f) {
  uint32_t u = __builtin_bit_cast(uint32_t, f);
  u += 0x7fffu + ((u >> 16) & 1u);          // round-to-nearest-even
  return (u16)(u >> 16);
}

__device__ __forceinline__ float bf2f(u16 h) {
  return __builtin_bit_cast(float, (uint32_t)h << 16);
}

__device__ __forceinline__ void async_cp16(const void* g, void* l) {
  __builtin_amdgcn_global_load_lds(
      (const __attribute__((address_space(1))) uint32_t*)g,
      (__attribute__((address_space(3))) uint32_t*)l, 16, 0, 0);
}

// cast x | features | prototypes -> contiguous bf16 region in ws (8 elem/thread)
__global__ __launch_bounds__(256) void cast3(
    const float* __restrict__ x, const float* __restrict__ f,
    const float* __restrict__ p, u16* __restrict__ dst,
    int n1, int n2, int n3) {
  int i = (blockIdx.x * 256 + threadIdx.x) * 8;
  const float* src;
  int local;
  if (i < n1) { src = x; local = i; }
  else if (i < n1 + n2) { src = f; local = i - n1; }
  else if (i < n1 + n2 + n3) { src = p; local = i - n1 - n2; }
  else return;
  f4 a = *(const f4*)(src + local);
  f4 b = *(const f4*)(src + local + 4);
  u16x8 o;
  o[0] = f2bf(a.x); o[1] = f2bf(a.y); o[2] = f2bf(a.z); o[3] = f2bf(a.w);
  o[4] = f2bf(b.x); o[5] = f2bf(b.y); o[6] = f2bf(b.z); o[7] = f2bf(b.w);
  *(u16x8*)(dst + i) = o;
}

// ---- shared main loop (TM=128, TN=128): C += A @ B^T with 32x32x16 MFMA ----
// A,B pre-offset to tile base row; 16B-chunk XOR swizzle (0 bank conflicts).
// Wave grid 2x2: wave covers 64 rows x 64 cols = 2x2 acc tiles of 32x32.
// 16 MFMA / K-step / wave between the two barriers (66 FLOP/staged-byte).
__device__ __forceinline__ void mainloop(
    const u16* __restrict__ A, const u16* __restrict__ B, int K,
    int kbeg, int kend, int tid, u16* lds, f32x16 (&acc)[2][2]) {
  constexpr int TM = 128, TN = 128, BK = 64;
  const int lane = tid & 63;
  const int wave = tid >> 6;
  const int wrow = wave >> 1, wcol = wave & 1;

  for (int k0 = kbeg; k0 < kend; k0 += BK) {
    #pragma unroll
    for (int it = 0; it < TM / 32; ++it) {
      int c = it * 256 + tid;            // chunk index = LDS position
      int row = c >> 3, pc = c & 7;
      int gc = pc ^ (row & 7);           // which global 16B chunk lands here
      async_cp16(A + (size_t)row * K + (k0 + gc * 8),
                 &lds[(it * 256 + wave * 64) * 8]);
    }
    #pragma unroll
    for (int it = 0; it < TN / 32; ++it) {
      int c = it * 256 + tid;
      int row = c >> 3, pc = c & 7;
      int gc = pc ^ (row & 7);
      async_cp16(B + (size_t)row * K + (k0 + gc * 8),
                 &lds[TM * 64 + (it * 256 + wave * 64) * 8]);
    }
    __syncthreads();

    #pragma unroll
    for (int s = 0; s < 4; ++s) {        // 4 k-steps of K=16
      const int h = s * 2 + (lane >> 5); // 16B chunk along K this lane needs
      bf16x8 bfr[2], afr[2];
      #pragma unroll
      for (int j = 0; j < 2; ++j) {
        const int rb = wcol * 64 + j * 32 + (lane & 31);
        bfr[j] = *(const bf16x8*)&lds[TM * 64 + (rb * 8 + (h ^ (rb & 7))) * 8];
      }
      #pragma unroll
      for (int i = 0; i < 2; ++i) {
        const int ra = wrow * 64 + i * 32 + (lane & 31);
        afr[i] = *(const bf16x8*)&lds[(ra * 8 + (h ^ (ra & 7))) * 8];
      }
      #pragma unroll
      for (int i = 0; i < 2; ++i)
        #pragma unroll
        for (int j = 0; j < 2; ++j)
          acc[i][j] = __builtin_amdgcn_mfma_f32_32x32x16_bf16(
              afr[i], bfr[j], acc[i][j], 0, 0, 0);
    }
    __syncthreads();
  }
}

// 32x32 C/D mapping (m74/m101 verified): col = lane&31,
// row = (reg&3) + 8*(reg>>2) + 4*(lane>>5), reg in [0,16).

// ---- GEMM1+GEMM2 merged: [x; proto](4608 x 1024) @ feat^T, tile 128x128 ----
// x-rows  -> Acat[row, f]=xf*relu(xf), Acat[row, 2048+f]=1-relu(xf)
// p-rows  -> Bcat[row, f]=th*c-al*(1-pres), Bcat[row, 2048+f]=-be*c
// Epilogue: LDS transpose (stride 136 u16 = 17x16B) -> 128B-coalesced stores.
__global__ __launch_bounds__(256) void gemm12(
    const u16* __restrict__ xb, const u16* __restrict__ pb,
    const u16* __restrict__ fb, u16* __restrict__ Acat, u16* __restrict__ Bcat,
    const float* __restrict__ alpha, const float* __restrict__ beta,
    const float* __restrict__ theta) {
  constexpr int TM = 128, TN = 128, K = 1024, N = 2048;
  constexpr int TSTRIDE = 136;           // u16; 272B rows = 17*16B aligned
  __shared__ u16 lds[17408];             // mainloop 32768B; transpose 34816B

  const int tid = threadIdx.x;
  const int lane = tid & 63;
  const int wave = tid >> 6;
  const int wrow = wave >> 1, wcol = wave & 1;
  const int bm_all = blockIdx.x * TM;
  const int bn = blockIdx.y * TN;
  const bool is_x = bm_all < 4096;       // block purely x or proto (4096%128==0)
  const u16* A = is_x ? xb + (size_t)bm_all * K : pb + (size_t)(bm_all - 4096) * K;
  const u16* B = fb + (size_t)bn * K;

  f32x16 acc[2][2] = {};
  mainloop(A, B, K, 0, K, tid, lds, acc);

  float th = 0.f, al = 0.f, be = 0.f;
  if (!is_x) { th = theta[0]; al = alpha[0]; be = beta[0]; }
  u16* dst = is_x ? Acat : Bcat;
  const int rowbase = is_x ? bm_all : bm_all - 4096;
  const int rquad = 4 * (lane >> 5);

  #pragma unroll
  for (int half = 0; half < 2; ++half) {
    __syncthreads();   // protect lds reuse (mainloop end / previous half's reads)
    #pragma unroll
    for (int i = 0; i < 2; ++i) {
      #pragma unroll
      for (int j = 0; j < 2; ++j) {
        const int cl = wcol * 64 + j * 32 + (lane & 31);
        #pragma unroll
        for (int r = 0; r < 16; ++r) {
          const int rl = wrow * 64 + i * 32 + (r & 3) + 8 * (r >> 2) + rquad;
          float v = acc[i][j][r];
          float pres = v > 0.f ? v : 0.f;
          float o;
          if (is_x) o = half == 0 ? v * pres : 1.f - pres;
          else {
            float cc = v * pres;
            o = half == 0 ? th * cc - al * (1.f - pres) : -be * cc;
          }
          lds[rl * TSTRIDE + cl] = f2bf(o);
        }
      }
    }
    __syncthreads();
    #pragma unroll
    for (int v = 0; v < 8; ++v) {
      const int rl = v * 16 + (tid >> 4);
      const int c8 = (tid & 15) * 8;
      u16x8 vec = *(const u16x8*)&lds[rl * TSTRIDE + c8];
      *(u16x8*)&dst[(size_t)(rowbase + rl) * (2 * N) + bn + c8 + half * N] = vec;
    }
  }
}

// ---- GEMM3 split-K: part[z] = Acat @ Bcat^T partial (bf16), tile 128x128 ----
// KSPLIT=4, grid 32x4x4 = 512 blocks. Partials bf16 thread-linear:
// tile = 16384 u16; chunk q = i*4 + j*2 + h (h = reg-octet), 2048 u16 each.
__global__ __launch_bounds__(256) void gemm3(
    const u16* __restrict__ Acat, const u16* __restrict__ Bcat,
    u16* __restrict__ part) {
  constexpr int TM = 128, TN = 128, K = 4096, KSPLIT = 4;
  __shared__ u16 lds[16384];             // 32768 B

  const int tid = threadIdx.x;
  const int bm = blockIdx.x * TM;
  const int bn = blockIdx.y * TN;
  const int kbeg = blockIdx.z * (K / KSPLIT);
  const int kend = kbeg + (K / KSPLIT);

  f32x16 acc[2][2] = {};
  mainloop(Acat + (size_t)bm * K, Bcat + (size_t)bn * K, K, kbeg, kend,
           tid, lds, acc);

  const size_t pbase =
      ((size_t)blockIdx.z * 128 + blockIdx.y * 32 + blockIdx.x) * 16384;
  #pragma unroll
  for (int i = 0; i < 2; ++i)
    #pragma unroll
    for (int j = 0; j < 2; ++j)
      #pragma unroll
      for (int h = 0; h < 2; ++h) {
        u16x8 o;
        #pragma unroll
        for (int e = 0; e < 8; ++e) o[e] = f2bf(acc[i][j][h * 8 + e]);
        *(u16x8*)&part[pbase + (size_t)(i * 4 + j * 2 + h) * 2048 + tid * 8] = o;
      }
}

// ---- reduce bf16 partials over z=0..4, scatter fp32 to out ----
// 1024 blocks: one q-chunk per block (tileId = bx>>3, q = bx&7). Mirrors
// gemm3 map: q = i*4+j*2+h; reg = h*8+e; row = bm + wrow*64 + i*32 +
// (reg&3)+8*(reg>>2)+4*(lane>>5); col = bn + wcol*64 + j*32 + (lane&31).
__global__ __launch_bounds__(256) void reduce4(
    const u16* __restrict__ part, float* __restrict__ out) {
  constexpr int N = 512;
  const int tid = threadIdx.x;
  const int lane = tid & 63;
  const int wave = tid >> 6;
  const int wrow = wave >> 1, wcol = wave & 1;
  const int tileId = blockIdx.x >> 3;      // 0..127 = by*32+bx
  const int q = blockIdx.x & 7;
  const int bm = (tileId & 31) * 128;
  const int bn = (tileId >> 5) * 128;

  float v[8] = {};
  #pragma unroll
  for (int z = 0; z < 4; ++z) {
    u16x8 u = *(const u16x8*)&part[((size_t)z * 128 + tileId) * 16384 +
                                   (size_t)q * 2048 + tid * 8];
    #pragma unroll
    for (int e = 0; e < 8; ++e) v[e] += bf2f(u[e]);
  }
  const int i = q >> 2, j = (q >> 1) & 1, h = q & 1;
  const int gc = bn + wcol * 64 + j * 32 + (lane & 31);
  const int grb = bm + wrow * 64 + i * 32 + 4 * (lane >> 5);
  #pragma unroll
  for (int e = 0; e < 8; ++e) {
    const int reg = h * 8 + e;
    out[(size_t)(grb + (reg & 3) + 8 * (reg >> 2)) * N + gc] = v[e];
  }
}

extern "C" void kernel_launch(void* const* d_in, const int* in_sizes, int n_in,
                              void* d_out, int out_size, void* d_ws, size_t ws_size,
                              hipStream_t stream) {
  const float* x     = (const float*)d_in[0];
  const float* feat  = (const float*)d_in[1];
  const float* proto = (const float*)d_in[2];
  const float* alpha = (const float*)d_in[3];
  const float* beta  = (const float*)d_in[4];
  const float* theta = (const float*)d_in[5];
  float* out = (float*)d_out;

  constexpr int Bb = 4096, Ii = 1024, Pp = 512, Ff = 2048;

  // ws layout (NO aliasing — R12 defensive change): casts | Acat | Bcat | part.
  // Total ~88 MB of the 256 MiB workspace.
  char* ws = (char*)d_ws;
  u16* xb   = (u16*)ws;                               // 8.4 MB
  u16* fb   = xb + (size_t)Bb * Ii;                   // 4.2 MB
  u16* pb   = fb + (size_t)Ff * Ii;                   // 1.0 MB
  size_t r0 = 33554432;                               // 32 MiB region0 (casts)
  u16* Acat = (u16*)(ws + r0);                        // 33.6 MB
  u16* Bcat = Acat + (size_t)Bb * 2 * Ff;             // 4.2 MB
  u16* part = Bcat + (size_t)Pp * 2 * Ff;             // 16.8 MB (dedicated)

  const int n1 = Bb * Ii, n2 = Ff * Ii, n3 = Pp * Ii;
  cast3<<<((n1 + n2 + n3) / 8 + 255) / 256, 256, 0, stream>>>(
      x, feat, proto, xb, n1, n2, n3);

  // merged GEMM1+GEMM2: M=4608 (36 row-tiles of 128), N=2048 (16 col-tiles of 128)
  gemm12<<<dim3(36, 16), 256, 0, stream>>>(xb, pb, fb, Acat, Bcat, alpha, beta, theta);

  // GEMM3: 4096x512, K=4096 split 4 ways -> 512 blocks, bf16 partials
  gemm3<<<dim3(Bb / 128, Pp / 128, 4), 256, 0, stream>>>(Acat, Bcat, part);

  // reduce z=0..4 -> out (8 blocks per tile, one q-chunk each)
  reduce4<<<1024, 256, 0, stream>>>(part, out);
}

// Round 2
// 139.711 us; speedup vs baseline: 1.0521x; 1.0521x over previous
//
#include <hip/hip_runtime.h>
#include <cstdint>

typedef __attribute__((ext_vector_type(8))) short bf16x8;    // 8 bf16 = 4 VGPRs
typedef __attribute__((ext_vector_type(16))) float f32x16;   // 32x32 MFMA C/D
typedef __attribute__((ext_vector_type(4))) float f4;
typedef __attribute__((ext_vector_type(8))) unsigned short u16x8;
typedef unsigned short u16;

// JOURNAL:
// R6: __launch_bounds__(256,6) forced VGPR 72->40, scratch spills (+36MB traffic).
// R7: device-scope __threadfence() reduction inside gemm3 = L2 writeback storms.
// R8: (256,8) neutral; residency saturated ~4 blocks/CU.
// R9: 32x32x16 MFMA beats 16x16x32 (-5us). BEST = 148.4us.
// R10: 256x64/KSPLIT=8 neutral -- confounded (intensity 44->52 AND 2x partials).
// R11: part aliased cast region -> GPU abort. R12: dedicated region. 142.7us.
// R13 FAILED: TN 64->128 => 47.2us gemm12 (was ~41). Counters: Occupancy 12%
//      (576 blocks = 2.25/CU), MfmaUtil 15%. Tile intensity was NOT the wall;
//      the serial vmcnt(0)-drain per K-step is (at R=2 no cross-block hiding).
//      Bank conflicts 2.5M = epilogue b16 pair-writes (2-way = free, benign).
// R14 (this round): 2-phase double-buffered mainloop (T3/T4 minimum recipe):
//      STAGE(next) issued BEFORE compute(cur); counted s_waitcnt vmcnt(8) +
//      raw s_barrier (no vmcnt(0) drain in steady state). LDS 64KB (2 buf),
//      2 blocks/CU. Predict gemm12 47->~30us, gemm3 ~40->~25, total ~110.

__device__ __forceinline__ u16 f2bf(float f) {
  uint32_t u = __builtin_bit_cast(uint32_t, f);
  u += 0x7fffu + ((u >> 16) & 1u);          // round-to-nearest-even
  return (u16)(u >> 16);
}

__device__ __forceinline__ float bf2f(u16 h) {
  return __builtin_bit_cast(float, (uint32_t)h << 16);
}

__device__ __forceinline__ void async_cp16(const void* g, void* l) {
  __builtin_amdgcn_global_load_lds(
      (const __attribute__((address_space(1))) uint32_t*)g,
      (__attribute__((address_space(3))) uint32_t*)l, 16, 0, 0);
}

// cast x | features | prototypes -> contiguous bf16 region in ws (8 elem/thread)
__global__ __launch_bounds__(256) void cast3(
    const float* __restrict__ x, const float* __restrict__ f,
    const float* __restrict__ p, u16* __restrict__ dst,
    int n1, int n2, int n3) {
  int i = (blockIdx.x * 256 + threadIdx.x) * 8;
  const float* src;
  int local;
  if (i < n1) { src = x; local = i; }
  else if (i < n1 + n2) { src = f; local = i - n1; }
  else if (i < n1 + n2 + n3) { src = p; local = i - n1 - n2; }
  else return;
  f4 a = *(const f4*)(src + local);
  f4 b = *(const f4*)(src + local + 4);
  u16x8 o;
  o[0] = f2bf(a.x); o[1] = f2bf(a.y); o[2] = f2bf(a.z); o[3] = f2bf(a.w);
  o[4] = f2bf(b.x); o[5] = f2bf(b.y); o[6] = f2bf(b.z); o[7] = f2bf(b.w);
  *(u16x8*)(dst + i) = o;
}

// ---- 2-phase pipelined main loop (TM=128, TN=128, BK=64) ----
// C += A @ B^T with 32x32x16 MFMA. 16B-chunk XOR swizzle (0 bank conflicts).
// Wave grid 2x2: wave covers 64x64 = 2x2 acc tiles of 32x32.
// Double-buffered LDS; next tile's 8 global_load_lds issued BEFORE compute,
// then counted s_waitcnt vmcnt(8) (NOT 0) + raw s_barrier: next-tile loads
// stay in flight across the whole compute phase (T3/T4 minimum recipe).

__device__ __forceinline__ void stage_tile(
    const u16* __restrict__ A, const u16* __restrict__ B, int K,
    int k0, int tid, u16* L) {
  constexpr int TM = 128, TN = 128;
  const int wave = tid >> 6;
  #pragma unroll
  for (int it = 0; it < TM / 32; ++it) {
    int c = it * 256 + tid;            // chunk index = LDS position
    int row = c >> 3, pc = c & 7;
    int gc = pc ^ (row & 7);           // which global 16B chunk lands here
    async_cp16(A + (size_t)row * K + (k0 + gc * 8),
               &L[(it * 256 + wave * 64) * 8]);
  }
  #pragma unroll
  for (int it = 0; it < TN / 32; ++it) {
    int c = it * 256 + tid;
    int row = c >> 3, pc = c & 7;
    int gc = pc ^ (row & 7);
    async_cp16(B + (size_t)row * K + (k0 + gc * 8),
               &L[TM * 64 + (it * 256 + wave * 64) * 8]);
  }
}

__device__ __forceinline__ void compute_tile(
    const u16* L, int lane, int wrow, int wcol, f32x16 (&acc)[2][2]) {
  constexpr int TM = 128;
  #pragma unroll
  for (int s = 0; s < 4; ++s) {        // 4 k-steps of K=16
    const int h = s * 2 + (lane >> 5); // 16B chunk along K this lane needs
    bf16x8 bfr[2], afr[2];
    #pragma unroll
    for (int j = 0; j < 2; ++j) {
      const int rb = wcol * 64 + j * 32 + (lane & 31);
      bfr[j] = *(const bf16x8*)&L[TM * 64 + (rb * 8 + (h ^ (rb & 7))) * 8];
    }
    #pragma unroll
    for (int i = 0; i < 2; ++i) {
      const int ra = wrow * 64 + i * 32 + (lane & 31);
      afr[i] = *(const bf16x8*)&L[(ra * 8 + (h ^ (ra & 7))) * 8];
    }
    #pragma unroll
    for (int i = 0; i < 2; ++i)
      #pragma unroll
      for (int j = 0; j < 2; ++j)
        acc[i][j] = __builtin_amdgcn_mfma_f32_32x32x16_bf16(
            afr[i], bfr[j], acc[i][j], 0, 0, 0);
  }
}

__device__ __forceinline__ void mainloop(
    const u16* __restrict__ A, const u16* __restrict__ B, int K,
    int kbeg, int kend, int tid, u16* lds, f32x16 (&acc)[2][2]) {
  constexpr int BK = 64;
  constexpr int BUF = 16384;           // u16 per LDS buffer (32 KiB)
  const int lane = tid & 63;
  const int wave = tid >> 6;
  const int wrow = wave >> 1, wcol = wave & 1;

  stage_tile(A, B, K, kbeg, tid, lds); // prologue: tile 0 -> buf 0
  int cur = 0;
  for (int k0 = kbeg; k0 < kend; k0 += BK) {
    if (k0 + BK < kend) {
      // issue next tile into the other buffer, then wait ONLY the 8 older
      // loads (current tile); next tile's 8 remain in flight during compute.
      stage_tile(A, B, K, k0 + BK, tid, lds + (cur ^ 1) * BUF);
      asm volatile("s_waitcnt vmcnt(8)" ::: "memory");
    } else {
      asm volatile("s_waitcnt vmcnt(0)" ::: "memory");
    }
    __builtin_amdgcn_s_barrier();      // all waves: current buffer complete
    compute_tile(lds + cur * BUF, lane, wrow, wcol, acc);
    __builtin_amdgcn_s_barrier();      // all waves done reading before next
    cur ^= 1;                          // iter overwrites this buffer
  }
}

// 32x32 C/D mapping (m74/m101 verified): col = lane&31,
// row = (reg&3) + 8*(reg>>2) + 4*(lane>>5), reg in [0,16).

// ---- GEMM1+GEMM2 merged: [x; proto](4608 x 1024) @ feat^T, tile 128x128 ----
// x-rows  -> Acat[row, f]=xf*relu(xf), Acat[row, 2048+f]=1-relu(xf)
// p-rows  -> Bcat[row, f]=th*c-al*(1-pres), Bcat[row, 2048+f]=-be*c
// Epilogue: LDS transpose (stride 136 u16 = 17x16B) -> 128B-coalesced stores.
__global__ __launch_bounds__(256) void gemm12(
    const u16* __restrict__ xb, const u16* __restrict__ pb,
    const u16* __restrict__ fb, u16* __restrict__ Acat, u16* __restrict__ Bcat,
    const float* __restrict__ alpha, const float* __restrict__ beta,
    const float* __restrict__ theta) {
  constexpr int TM = 128, K = 1024, N = 2048;
  constexpr int TSTRIDE = 136;           // u16; 272B rows = 17*16B aligned
  __shared__ u16 lds[32768];             // 64 KiB: 2 mainloop bufs; transpose reuses

  const int tid = threadIdx.x;
  const int lane = tid & 63;
  const int wave = tid >> 6;
  const int wrow = wave >> 1, wcol = wave & 1;
  const int bm_all = blockIdx.x * TM;
  const int bn = blockIdx.y * 128;
  const bool is_x = bm_all < 4096;       // block purely x or proto (4096%128==0)
  const u16* A = is_x ? xb + (size_t)bm_all * K : pb + (size_t)(bm_all - 4096) * K;
  const u16* B = fb + (size_t)bn * K;

  f32x16 acc[2][2] = {};
  mainloop(A, B, K, 0, K, tid, lds, acc);

  float th = 0.f, al = 0.f, be = 0.f;
  if (!is_x) { th = theta[0]; al = alpha[0]; be = beta[0]; }
  u16* dst = is_x ? Acat : Bcat;
  const int rowbase = is_x ? bm_all : bm_all - 4096;
  const int rquad = 4 * (lane >> 5);

  #pragma unroll
  for (int half = 0; half < 2; ++half) {
    __syncthreads();   // protect lds reuse (mainloop end / previous half's reads)
    #pragma unroll
    for (int i = 0; i < 2; ++i) {
      #pragma unroll
      for (int j = 0; j < 2; ++j) {
        const int cl = wcol * 64 + j * 32 + (lane & 31);
        #pragma unroll
        for (int r = 0; r < 16; ++r) {
          const int rl = wrow * 64 + i * 32 + (r & 3) + 8 * (r >> 2) + rquad;
          float v = acc[i][j][r];
          float pres = v > 0.f ? v : 0.f;
          float o;
          if (is_x) o = half == 0 ? v * pres : 1.f - pres;
          else {
            float cc = v * pres;
            o = half == 0 ? th * cc - al * (1.f - pres) : -be * cc;
          }
          lds[rl * TSTRIDE + cl] = f2bf(o);
        }
      }
    }
    __syncthreads();
    #pragma unroll
    for (int v = 0; v < 8; ++v) {
      const int rl = v * 16 + (tid >> 4);
      const int c8 = (tid & 15) * 8;
      u16x8 vec = *(const u16x8*)&lds[rl * TSTRIDE + c8];
      *(u16x8*)&dst[(size_t)(rowbase + rl) * (2 * N) + bn + c8 + half * N] = vec;
    }
  }
}

// ---- GEMM3 split-K: part[z] = Acat @ Bcat^T partial (bf16), tile 128x128 ----
// KSPLIT=4, grid 32x4x4 = 512 blocks (exactly 2 waves of 256 CUs).
// Partials bf16 thread-linear: tile = 16384 u16; chunk q = i*4 + j*2 + h.
__global__ __launch_bounds__(256) void gemm3(
    const u16* __restrict__ Acat, const u16* __restrict__ Bcat,
    u16* __restrict__ part) {
  constexpr int TM = 128, TN = 128, K = 4096, KSPLIT = 4;
  __shared__ u16 lds[32768];             // 64 KiB: 2 mainloop bufs

  const int tid = threadIdx.x;
  const int bm = blockIdx.x * TM;
  const int bn = blockIdx.y * TN;
  const int kbeg = blockIdx.z * (K / KSPLIT);
  const int kend = kbeg + (K / KSPLIT);

  f32x16 acc[2][2] = {};
  mainloop(Acat + (size_t)bm * K, Bcat + (size_t)bn * K, K, kbeg, kend,
           tid, lds, acc);

  const size_t pbase =
      ((size_t)blockIdx.z * 128 + blockIdx.y * 32 + blockIdx.x) * 16384;
  #pragma unroll
  for (int i = 0; i < 2; ++i)
    #pragma unroll
    for (int j = 0; j < 2; ++j)
      #pragma unroll
      for (int h = 0; h < 2; ++h) {
        u16x8 o;
        #pragma unroll
        for (int e = 0; e < 8; ++e) o[e] = f2bf(acc[i][j][h * 8 + e]);
        *(u16x8*)&part[pbase + (size_t)(i * 4 + j * 2 + h) * 2048 + tid * 8] = o;
      }
}

// ---- reduce bf16 partials over z=0..4, scatter fp32 to out ----
// 1024 blocks: one q-chunk per block (tileId = bx>>3, q = bx&7). Mirrors
// gemm3 map: q = i*4+j*2+h; reg = h*8+e; row = bm + wrow*64 + i*32 +
// (reg&3)+8*(reg>>2)+4*(lane>>5); col = bn + wcol*64 + j*32 + (lane&31).
__global__ __launch_bounds__(256) void reduce4(
    const u16* __restrict__ part, float* __restrict__ out) {
  constexpr int N = 512;
  const int tid = threadIdx.x;
  const int lane = tid & 63;
  const int wave = tid >> 6;
  const int wrow = wave >> 1, wcol = wave & 1;
  const int tileId = blockIdx.x >> 3;      // 0..127 = by*32+bx
  const int q = blockIdx.x & 7;
  const int bm = (tileId & 31) * 128;
  const int bn = (tileId >> 5) * 128;

  float v[8] = {};
  #pragma unroll
  for (int z = 0; z < 4; ++z) {
    u16x8 u = *(const u16x8*)&part[((size_t)z * 128 + tileId) * 16384 +
                                   (size_t)q * 2048 + tid * 8];
    #pragma unroll
    for (int e = 0; e < 8; ++e) v[e] += bf2f(u[e]);
  }
  const int i = q >> 2, j = (q >> 1) & 1, h = q & 1;
  const int gc = bn + wcol * 64 + j * 32 + (lane & 31);
  const int grb = bm + wrow * 64 + i * 32 + 4 * (lane >> 5);
  #pragma unroll
  for (int e = 0; e < 8; ++e) {
    const int reg = h * 8 + e;
    out[(size_t)(grb + (reg & 3) + 8 * (reg >> 2)) * N + gc] = v[e];
  }
}

extern "C" void kernel_launch(void* const* d_in, const int* in_sizes, int n_in,
                              void* d_out, int out_size, void* d_ws, size_t ws_size,
                              hipStream_t stream) {
  const float* x     = (const float*)d_in[0];
  const float* feat  = (const float*)d_in[1];
  const float* proto = (const float*)d_in[2];
  const float* alpha = (const float*)d_in[3];
  const float* beta  = (const float*)d_in[4];
  const float* theta = (const float*)d_in[5];
  float* out = (float*)d_out;

  constexpr int Bb = 4096, Ii = 1024, Pp = 512, Ff = 2048;

  // ws layout (NO aliasing — R12 defensive change): casts | Acat | Bcat | part.
  // Total ~88 MB of the 256 MiB workspace.
  char* ws = (char*)d_ws;
  u16* xb   = (u16*)ws;                               // 8.4 MB
  u16* fb   = xb + (size_t)Bb * Ii;                   // 4.2 MB
  u16* pb   = fb + (size_t)Ff * Ii;                   // 1.0 MB
  size_t r0 = 33554432;                               // 32 MiB region0 (casts)
  u16* Acat = (u16*)(ws + r0);                        // 33.6 MB
  u16* Bcat = Acat + (size_t)Bb * 2 * Ff;             // 4.2 MB
  u16* part = Bcat + (size_t)Pp * 2 * Ff;             // 16.8 MB (dedicated)

  const int n1 = Bb * Ii, n2 = Ff * Ii, n3 = Pp * Ii;
  cast3<<<((n1 + n2 + n3) / 8 + 255) / 256, 256, 0, stream>>>(
      x, feat, proto, xb, n1, n2, n3);

  // merged GEMM1+GEMM2: M=4608 (36 row-tiles of 128), N=2048 (16 col-tiles of 128)
  gemm12<<<dim3(36, 16), 256, 0, stream>>>(xb, pb, fb, Acat, Bcat, alpha, beta, theta);

  // GEMM3: 4096x512, K=4096 split 4 ways -> 512 blocks, bf16 partials
  gemm3<<<dim3(Bb / 128, Pp / 128, 4), 256, 0, stream>>>(Acat, Bcat, part);

  // reduce z=0..4 -> out (8 blocks per tile, one q-chunk each)
  reduce4<<<1024, 256, 0, stream>>>(part, out);
}

// Round 4
// 137.656 us; speedup vs baseline: 1.0678x; 1.0149x over previous
//
#include <hip/hip_runtime.h>
#include <cstdint>

typedef __attribute__((ext_vector_type(8))) short bf16x8;    // 8 bf16 = 4 VGPRs
typedef __attribute__((ext_vector_type(16))) float f32x16;   // 32x32 MFMA C/D
typedef __attribute__((ext_vector_type(4))) float f4;
typedef __attribute__((ext_vector_type(8))) unsigned short u16x8;
typedef unsigned short u16;

// JOURNAL:
// R6: __launch_bounds__(256,6) forced VGPR 72->40, scratch spills (+36MB traffic).
// R7: device-scope __threadfence() reduction inside gemm3 = L2 writeback storms.
// R8: (256,8) neutral; residency saturated ~4 blocks/CU.
// R9: 32x32x16 MFMA beats 16x16x32 (-5us). BEST = 148.4us.
// R10: 256x64/KSPLIT=8 neutral -- confounded (intensity 44->52 AND 2x partials).
// R11: part aliased cast region -> GPU abort. R12: dedicated region. 142.7us.
// R13 FAILED: TN 64->128 => 47.2us gemm12. Occupancy 12%, MfmaUtil 15%.
// R14 PARTIAL: 2-phase dbuf + counted vmcnt(8): 147->139.7. Both GEMMs ~41us
//      (= m132's 64KB-LDS/2-block 508 TF datapoint). Staging math from R13
//      counters: 288MB cache reads / 41us = ~7 TB/s = L3-side ceiling; L2
//      misses because round-robin XCD dispatch scatters operand panels.
// R15: XCD supertile swizzle — NO DATA (container failed twice, infra-level;
//      no pytest/correctness signal). Decode re-audited: both maps bijective,
//      no divergence introduced, pbase mirror unchanged. Retrying unchanged.
// R16 (this round): identical kernel to R15, re-run. Predict both GEMMs
//      ~41->~25us, total ->~108. Neutral => L2-locality theory wrong ->
//      8-phase restructure next.

__device__ __forceinline__ u16 f2bf(float f) {
  uint32_t u = __builtin_bit_cast(uint32_t, f);
  u += 0x7fffu + ((u >> 16) & 1u);          // round-to-nearest-even
  return (u16)(u >> 16);
}

__device__ __forceinline__ float bf2f(u16 h) {
  return __builtin_bit_cast(float, (uint32_t)h << 16);
}

__device__ __forceinline__ void async_cp16(const void* g, void* l) {
  __builtin_amdgcn_global_load_lds(
      (const __attribute__((address_space(1))) uint32_t*)g,
      (__attribute__((address_space(3))) uint32_t*)l, 16, 0, 0);
}

// cast x | features | prototypes -> contiguous bf16 region in ws (8 elem/thread)
__global__ __launch_bounds__(256) void cast3(
    const float* __restrict__ x, const float* __restrict__ f,
    const float* __restrict__ p, u16* __restrict__ dst,
    int n1, int n2, int n3) {
  int i = (blockIdx.x * 256 + threadIdx.x) * 8;
  const float* src;
  int local;
  if (i < n1) { src = x; local = i; }
  else if (i < n1 + n2) { src = f; local = i - n1; }
  else if (i < n1 + n2 + n3) { src = p; local = i - n1 - n2; }
  else return;
  f4 a = *(const f4*)(src + local);
  f4 b = *(const f4*)(src + local + 4);
  u16x8 o;
  o[0] = f2bf(a.x); o[1] = f2bf(a.y); o[2] = f2bf(a.z); o[3] = f2bf(a.w);
  o[4] = f2bf(b.x); o[5] = f2bf(b.y); o[6] = f2bf(b.z); o[7] = f2bf(b.w);
  *(u16x8*)(dst + i) = o;
}

// ---- 2-phase pipelined main loop (TM=128, TN=128, BK=64) ----
// C += A @ B^T with 32x32x16 MFMA. 16B-chunk XOR swizzle (0 bank conflicts).
// Wave grid 2x2: wave covers 64x64 = 2x2 acc tiles of 32x32.
// Double-buffered LDS; next tile's 8 global_load_lds issued BEFORE compute,
// then counted s_waitcnt vmcnt(8) (NOT 0) + raw s_barrier: next-tile loads
// stay in flight across the whole compute phase (T3/T4 minimum recipe).

__device__ __forceinline__ void stage_tile(
    const u16* __restrict__ A, const u16* __restrict__ B, int K,
    int k0, int tid, u16* L) {
  constexpr int TM = 128, TN = 128;
  const int wave = tid >> 6;
  #pragma unroll
  for (int it = 0; it < TM / 32; ++it) {
    int c = it * 256 + tid;            // chunk index = LDS position
    int row = c >> 3, pc = c & 7;
    int gc = pc ^ (row & 7);           // which global 16B chunk lands here
    async_cp16(A + (size_t)row * K + (k0 + gc * 8),
               &L[(it * 256 + wave * 64) * 8]);
  }
  #pragma unroll
  for (int it = 0; it < TN / 32; ++it) {
    int c = it * 256 + tid;
    int row = c >> 3, pc = c & 7;
    int gc = pc ^ (row & 7);
    async_cp16(B + (size_t)row * K + (k0 + gc * 8),
               &L[TM * 64 + (it * 256 + wave * 64) * 8]);
  }
}

__device__ __forceinline__ void compute_tile(
    const u16* L, int lane, int wrow, int wcol, f32x16 (&acc)[2][2]) {
  constexpr int TM = 128;
  #pragma unroll
  for (int s = 0; s < 4; ++s) {        // 4 k-steps of K=16
    const int h = s * 2 + (lane >> 5); // 16B chunk along K this lane needs
    bf16x8 bfr[2], afr[2];
    #pragma unroll
    for (int j = 0; j < 2; ++j) {
      const int rb = wcol * 64 + j * 32 + (lane & 31);
      bfr[j] = *(const bf16x8*)&L[TM * 64 + (rb * 8 + (h ^ (rb & 7))) * 8];
    }
    #pragma unroll
    for (int i = 0; i < 2; ++i) {
      const int ra = wrow * 64 + i * 32 + (lane & 31);
      afr[i] = *(const bf16x8*)&L[(ra * 8 + (h ^ (ra & 7))) * 8];
    }
    #pragma unroll
    for (int i = 0; i < 2; ++i)
      #pragma unroll
      for (int j = 0; j < 2; ++j)
        acc[i][j] = __builtin_amdgcn_mfma_f32_32x32x16_bf16(
            afr[i], bfr[j], acc[i][j], 0, 0, 0);
  }
}

__device__ __forceinline__ void mainloop(
    const u16* __restrict__ A, const u16* __restrict__ B, int K,
    int kbeg, int kend, int tid, u16* lds, f32x16 (&acc)[2][2]) {
  constexpr int BK = 64;
  constexpr int BUF = 16384;           // u16 per LDS buffer (32 KiB)
  const int lane = tid & 63;
  const int wave = tid >> 6;
  const int wrow = wave >> 1, wcol = wave & 1;

  stage_tile(A, B, K, kbeg, tid, lds); // prologue: tile 0 -> buf 0
  int cur = 0;
  for (int k0 = kbeg; k0 < kend; k0 += BK) {
    if (k0 + BK < kend) {
      // issue next tile into the other buffer, then wait ONLY the 8 older
      // loads (current tile); next tile's 8 remain in flight during compute.
      stage_tile(A, B, K, k0 + BK, tid, lds + (cur ^ 1) * BUF);
      asm volatile("s_waitcnt vmcnt(8)" ::: "memory");
    } else {
      asm volatile("s_waitcnt vmcnt(0)" ::: "memory");
    }
    __builtin_amdgcn_s_barrier();      // all waves: current buffer complete
    compute_tile(lds + cur * BUF, lane, wrow, wcol, acc);
    __builtin_amdgcn_s_barrier();      // all waves done reading before next
    cur ^= 1;                          // iter overwrites this buffer
  }
}

// 32x32 C/D mapping (m74/m101 verified): col = lane&31,
// row = (reg&3) + 8*(reg>>2) + 4*(lane>>5), reg in [0,16).

// ---- GEMM1+GEMM2 merged: [x; proto](4608 x 1024) @ feat^T, tile 128x128 ----
// 1D grid 576; XCD-supertile decode: XCD k = bid%8 owns a 9x8 tile panel
// (kx=k%4, ky=k/4): x = kx*9 + slot/8, y = ky*8 + slot%8, slot = bid/8.
// Panel working set = 9 A-tiles (2.25MB) + 8 B-tiles (2MB) ~= 4MB L2.
// x-rows  -> Acat[row, f]=xf*relu(xf), Acat[row, 2048+f]=1-relu(xf)
// p-rows  -> Bcat[row, f]=th*c-al*(1-pres), Bcat[row, 2048+f]=-be*c
// Epilogue: LDS transpose (stride 136 u16 = 17x16B) -> 128B-coalesced stores.
__global__ __launch_bounds__(256) void gemm12(
    const u16* __restrict__ xb, const u16* __restrict__ pb,
    const u16* __restrict__ fb, u16* __restrict__ Acat, u16* __restrict__ Bcat,
    const float* __restrict__ alpha, const float* __restrict__ beta,
    const float* __restrict__ theta) {
  constexpr int TM = 128, K = 1024, N = 2048;
  constexpr int TSTRIDE = 136;           // u16; 272B rows = 17*16B aligned
  __shared__ u16 lds[32768];             // 64 KiB: 2 mainloop bufs; transpose reuses

  const int tid = threadIdx.x;
  const int lane = tid & 63;
  const int wave = tid >> 6;
  const int wrow = wave >> 1, wcol = wave & 1;

  // XCD-aware supertile decode (bijective: 576 = 8 * 72, panels 9x8)
  const int bid = blockIdx.x;
  const int xcd = bid & 7, slot = bid >> 3;        // xcd 0..7, slot 0..71
  const int xt = (xcd & 3) * 9 + (slot >> 3);      // 0..35
  const int yt = (xcd >> 2) * 8 + (slot & 7);      // 0..15

  const int bm_all = xt * TM;
  const int bn = yt * 128;
  const bool is_x = bm_all < 4096;       // block purely x or proto (4096%128==0)
  const u16* A = is_x ? xb + (size_t)bm_all * K : pb + (size_t)(bm_all - 4096) * K;
  const u16* B = fb + (size_t)bn * K;

  f32x16 acc[2][2] = {};
  mainloop(A, B, K, 0, K, tid, lds, acc);

  float th = 0.f, al = 0.f, be = 0.f;
  if (!is_x) { th = theta[0]; al = alpha[0]; be = beta[0]; }
  u16* dst = is_x ? Acat : Bcat;
  const int rowbase = is_x ? bm_all : bm_all - 4096;
  const int rquad = 4 * (lane >> 5);

  #pragma unroll
  for (int half = 0; half < 2; ++half) {
    __syncthreads();   // protect lds reuse (mainloop end / previous half's reads)
    #pragma unroll
    for (int i = 0; i < 2; ++i) {
      #pragma unroll
      for (int j = 0; j < 2; ++j) {
        const int cl = wcol * 64 + j * 32 + (lane & 31);
        #pragma unroll
        for (int r = 0; r < 16; ++r) {
          const int rl = wrow * 64 + i * 32 + (r & 3) + 8 * (r >> 2) + rquad;
          float v = acc[i][j][r];
          float pres = v > 0.f ? v : 0.f;
          float o;
          if (is_x) o = half == 0 ? v * pres : 1.f - pres;
          else {
            float cc = v * pres;
            o = half == 0 ? th * cc - al * (1.f - pres) : -be * cc;
          }
          lds[rl * TSTRIDE + cl] = f2bf(o);
        }
      }
    }
    __syncthreads();
    #pragma unroll
    for (int v = 0; v < 8; ++v) {
      const int rl = v * 16 + (tid >> 4);
      const int c8 = (tid & 15) * 8;
      u16x8 vec = *(const u16x8*)&lds[rl * TSTRIDE + c8];
      *(u16x8*)&dst[(size_t)(rowbase + rl) * (2 * N) + bn + c8 + half * N] = vec;
    }
  }
}

// ---- GEMM3 split-K: part[z] = Acat @ Bcat^T partial (bf16), tile 128x128 ----
// 1D grid 512; XCD-supertile decode: XCD k = bid%8 owns 16x * 4y * 1z
// (z = k/2, xh = k%2): x = xh*16 + slot/4, y = slot%4. Panel = 16 A-tiles
// (4MB) + 4 B-tiles (1MB). Partials bf16 thread-linear, chunk q = i*4+j*2+h.
__global__ __launch_bounds__(256) void gemm3(
    const u16* __restrict__ Acat, const u16* __restrict__ Bcat,
    u16* __restrict__ part) {
  constexpr int TM = 128, TN = 128, K = 4096, KSPLIT = 4;
  __shared__ u16 lds[32768];             // 64 KiB: 2 mainloop bufs

  const int tid = threadIdx.x;

  // XCD-aware supertile decode (bijective: 512 = 8 * 64, panels 16x4x1)
  const int bid = blockIdx.x;
  const int xcd = bid & 7, slot = bid >> 3;        // xcd 0..7, slot 0..63
  const int bz = xcd >> 1;                         // 0..3 (K quarter)
  const int bxt = (xcd & 1) * 16 + (slot >> 2);    // 0..31
  const int byt = slot & 3;                        // 0..3

  const int bm = bxt * TM;
  const int bn = byt * TN;
  const int kbeg = bz * (K / KSPLIT);
  const int kend = kbeg + (K / KSPLIT);

  f32x16 acc[2][2] = {};
  mainloop(Acat + (size_t)bm * K, Bcat + (size_t)bn * K, K, kbeg, kend,
           tid, lds, acc);

  const size_t pbase = ((size_t)bz * 128 + byt * 32 + bxt) * 16384;
  #pragma unroll
  for (int i = 0; i < 2; ++i)
    #pragma unroll
    for (int j = 0; j < 2; ++j)
      #pragma unroll
      for (int h = 0; h < 2; ++h) {
        u16x8 o;
        #pragma unroll
        for (int e = 0; e < 8; ++e) o[e] = f2bf(acc[i][j][h * 8 + e]);
        *(u16x8*)&part[pbase + (size_t)(i * 4 + j * 2 + h) * 2048 + tid * 8] = o;
      }
}

// ---- reduce bf16 partials over z=0..4, scatter fp32 to out ----
// 1024 blocks: one q-chunk per block (tileId = bx>>3, q = bx&7). Mirrors
// gemm3 map: q = i*4+j*2+h; reg = h*8+e; row = bm + wrow*64 + i*32 +
// (reg&3)+8*(reg>>2)+4*(lane>>5); col = bn + wcol*64 + j*32 + (lane&31).
__global__ __launch_bounds__(256) void reduce4(
    const u16* __restrict__ part, float* __restrict__ out) {
  constexpr int N = 512;
  const int tid = threadIdx.x;
  const int lane = tid & 63;
  const int wave = tid >> 6;
  const int wrow = wave >> 1, wcol = wave & 1;
  const int tileId = blockIdx.x >> 3;      // 0..127 = by*32+bx
  const int q = blockIdx.x & 7;
  const int bm = (tileId & 31) * 128;
  const int bn = (tileId >> 5) * 128;

  float v[8] = {};
  #pragma unroll
  for (int z = 0; z < 4; ++z) {
    u16x8 u = *(const u16x8*)&part[((size_t)z * 128 + tileId) * 16384 +
                                   (size_t)q * 2048 + tid * 8];
    #pragma unroll
    for (int e = 0; e < 8; ++e) v[e] += bf2f(u[e]);
  }
  const int i = q >> 2, j = (q >> 1) & 1, h = q & 1;
  const int gc = bn + wcol * 64 + j * 32 + (lane & 31);
  const int grb = bm + wrow * 64 + i * 32 + 4 * (lane >> 5);
  #pragma unroll
  for (int e = 0; e < 8; ++e) {
    const int reg = h * 8 + e;
    out[(size_t)(grb + (reg & 3) + 8 * (reg >> 2)) * N + gc] = v[e];
  }
}

extern "C" void kernel_launch(void* const* d_in, const int* in_sizes, int n_in,
                              void* d_out, int out_size, void* d_ws, size_t ws_size,
                              hipStream_t stream) {
  const float* x     = (const float*)d_in[0];
  const float* feat  = (const float*)d_in[1];
  const float* proto = (const float*)d_in[2];
  const float* alpha = (const float*)d_in[3];
  const float* beta  = (const float*)d_in[4];
  const float* theta = (const float*)d_in[5];
  float* out = (float*)d_out;

  constexpr int Bb = 4096, Ii = 1024, Pp = 512, Ff = 2048;

  // ws layout (NO aliasing — R12 defensive change): casts | Acat | Bcat | part.
  // Total ~88 MB of the 256 MiB workspace.
  char* ws = (char*)d_ws;
  u16* xb   = (u16*)ws;                               // 8.4 MB
  u16* fb   = xb + (size_t)Bb * Ii;                   // 4.2 MB
  u16* pb   = fb + (size_t)Ff * Ii;                   // 1.0 MB
  size_t r0 = 33554432;                               // 32 MiB region0 (casts)
  u16* Acat = (u16*)(ws + r0);                        // 33.6 MB
  u16* Bcat = Acat + (size_t)Bb * 2 * Ff;             // 4.2 MB
  u16* part = Bcat + (size_t)Pp * 2 * Ff;             // 16.8 MB (dedicated)

  const int n1 = Bb * Ii, n2 = Ff * Ii, n3 = Pp * Ii;
  cast3<<<((n1 + n2 + n3) / 8 + 255) / 256, 256, 0, stream>>>(
      x, feat, proto, xb, n1, n2, n3);

  // merged GEMM1+GEMM2: M=4608, N=2048; 1D grid 576 with XCD supertile decode
  gemm12<<<576, 256, 0, stream>>>(xb, pb, fb, Acat, Bcat, alpha, beta, theta);

  // GEMM3: 4096x512, K=4096 split 4 ways; 1D grid 512 with XCD supertile decode
  gemm3<<<512, 256, 0, stream>>>(Acat, Bcat, part);

  // reduce z=0..4 -> out (8 blocks per tile, one q-chunk each)
  reduce4<<<1024, 256, 0, stream>>>(part, out);
}